// Round 2
// baseline (273.374 us; speedup 1.0000x reference)
//
#include <hip/hip_runtime.h>
#include <math.h>
#include <float.h>
#include <limits.h>

// Problem constants
#define PIX    13824   // 64*216
#define QPIX   3456    // 32*108
#define QW     108
#define QH     32
#define NPTS   8192
#define MCAP   3072    // per-quadrant center capacity (expected ~2048, 26 sigma)
#define KTILES 54      // QPIX/64  (k4b key-groups)
#define KT2    27      // QPIX/128 (k4a key tiles)
#define SPLITS 9       // center-tile splits for k4a (1 x 256-wide tile each)
#define CTILE  256     // centers per k4a tile

// ---------------------------------------------------------------------------
// K1: feat/value linear maps + fold to [r][k][c] pixel-major + feat inv-norm
// ---------------------------------------------------------------------------
__global__ __launch_bounds__(256) void k1_linmaps(
    const float* __restrict__ x, const float* __restrict__ Wf, const float* __restrict__ bf,
    const float* __restrict__ Wv, const float* __restrict__ bv,
    float* __restrict__ featp, float* __restrict__ valp, float* __restrict__ invn)
{
    __shared__ float ssq[4][64];
    int t = threadIdx.x;
    int lane = t & 63;
    int q = t >> 6;                       // wave id -> o-group (wave-uniform)
    int pix = blockIdx.x * 64 + lane;     // 216*64 = 13824 exact
    int h = pix / 216;
    int w = pix - h * 216;
    int r = ((h >> 5) << 1) | (w >= QW ? 1 : 0);
    int k = (h & 31) * QW + (w >= QW ? w - QW : w);

    float xr[64];
    #pragma unroll
    for (int c = 0; c < 64; c++) xr[c] = x[c * PIX + pix];

    size_t base = ((size_t)(r * QPIX + k)) * 64 + q * 16;
    float ss = 0.0f;
    for (int i = 0; i < 16; i++) {
        int o = q * 16 + i;               // wave-uniform
        float af = bf[o], av = bv[o];
        #pragma unroll
        for (int c = 0; c < 64; c++) {
            af = fmaf(Wf[o * 64 + c], xr[c], af);
            av = fmaf(Wv[o * 64 + c], xr[c], av);
        }
        featp[base + i] = af;
        valp[base + i]  = av;
        ss += af * af;
    }
    ssq[q][lane] = ss;
    __syncthreads();
    if (q == 0) {
        float tot = ssq[0][lane] + ssq[1][lane] + ssq[2][lane] + ssq[3][lane];
        invn[r * QPIX + k] = 1.0f / fmaxf(sqrtf(tot), 1e-12f);
    }
}

// ---------------------------------------------------------------------------
// K2 (hierarchical, order-preserving compaction):
//   k2a: per-64-point-chunk quadrant counts (128 chunks)
//   k2b: per-quadrant exclusive scan of chunk counts (wave shfl scan)
//   k2c: ranked scatter using chunk base + ballot rank
// ---------------------------------------------------------------------------
__device__ __forceinline__ int point_quadrant(float px, float py) {
    // rh = 384/2 = 192 exact, rw = 1296/2 = 648 exact
    return ((py > 192.0f) ? 2 : 0) + ((px > 648.0f) ? 1 : 0);
}

__global__ __launch_bounds__(64) void k2a_count(
    const float* __restrict__ points, int* __restrict__ ccnt)
{
    int lane = threadIdx.x;
    int chunk = blockIdx.x;
    float2 p = ((const float2*)points)[chunk * 64 + lane];
    int q = point_quadrant(p.x, p.y);
    #pragma unroll
    for (int r = 0; r < 4; r++) {
        unsigned long long m = __ballot(q == r);
        if (lane == 0) ccnt[chunk * 4 + r] = __popcll(m);
    }
}

__global__ __launch_bounds__(256) void k2b_scan(
    const int* __restrict__ ccnt, int* __restrict__ cbase, int* __restrict__ counts)
{
    int t = threadIdx.x;
    int r = t >> 6;        // wave = quadrant
    int lane = t & 63;     // lane handles chunks 2*lane, 2*lane+1
    int c0 = ccnt[(2 * lane) * 4 + r];
    int c1 = ccnt[(2 * lane + 1) * 4 + r];
    int pair = c0 + c1;
    int incl = pair;
    #pragma unroll
    for (int d = 1; d < 64; d <<= 1) {
        int n = __shfl_up(incl, d, 64);
        if (lane >= d) incl += n;
    }
    int excl = incl - pair;
    cbase[r * 128 + 2 * lane]     = excl;
    cbase[r * 128 + 2 * lane + 1] = excl + c0;
    if (lane == 63) counts[r] = incl;
}

__global__ __launch_bounds__(64) void k2c_scatter(
    const float* __restrict__ points, const int* __restrict__ cbase,
    float* __restrict__ cp, int* __restrict__ slot)
{
    int lane = threadIdx.x;
    int chunk = blockIdx.x;
    int n = chunk * 64 + lane;
    float2 p = ((const float2*)points)[n];
    int q = point_quadrant(p.x, p.y);
    unsigned long long below = (lane == 0) ? 0ull : (~0ull >> (64 - lane));
    #pragma unroll
    for (int r = 0; r < 4; r++) {
        unsigned long long m = __ballot(q == r);
        if (q == r) {
            int pos = cbase[r * 128 + chunk] + __popcll(m & below);
            ((float2*)cp)[r * MCAP + pos] = p;
            slot[n] = r * MCAP + pos;
        }
    }
}

// ---------------------------------------------------------------------------
// K3: bilinear gather (border clamp) of feat & value at compacted points;
// slot m == K_r is the phantom (0,0) padded row.
// ---------------------------------------------------------------------------
__global__ __launch_bounds__(64) void k3_gather(
    const float* __restrict__ featp, const float* __restrict__ valp,
    const float* __restrict__ cp, const int* __restrict__ counts,
    float* __restrict__ cn, float* __restrict__ vc)
{
    int r = blockIdx.y;
    int m = blockIdx.x * 64 + threadIdx.x;
    int K = counts[r];
    int Mr = min(K + 1, MCAP);
    if (m >= Mr) return;
    float px = 0.0f, py = 0.0f;
    if (m < K) { float2 p = ((const float2*)cp)[r * MCAP + m]; px = p.x; py = p.y; }

    // mirror reference op order: grid = p/(S-1)*2-1 ; g = (grid+1)*(D/2)-0.5
    float gx = (px / 1295.0f * 2.0f - 1.0f + 1.0f) * 54.0f - 0.5f;
    float gy = (py / 383.0f  * 2.0f - 1.0f + 1.0f) * 16.0f - 0.5f;
    float x0 = floorf(gx), y0 = floorf(gy);
    float wx = gx - x0, wy = gy - y0;
    int x0i = (int)fminf(fmaxf(x0,         0.0f), 107.0f);
    int x1i = (int)fminf(fmaxf(x0 + 1.0f,  0.0f), 107.0f);
    int y0i = (int)fminf(fmaxf(y0,         0.0f), 31.0f);
    int y1i = (int)fminf(fmaxf(y0 + 1.0f,  0.0f), 31.0f);
    float w00 = (1.0f - wx) * (1.0f - wy);
    float w01 = wx * (1.0f - wy);
    float w10 = (1.0f - wx) * wy;
    float w11 = wx * wy;

    size_t b00 = ((size_t)(r * QPIX + y0i * QW + x0i)) * 64;
    size_t b01 = ((size_t)(r * QPIX + y0i * QW + x1i)) * 64;
    size_t b10 = ((size_t)(r * QPIX + y1i * QW + x0i)) * 64;
    size_t b11 = ((size_t)(r * QPIX + y1i * QW + x1i)) * 64;
    size_t ob  = ((size_t)(r * MCAP + m)) * 64;

    float fr[64];
    float ss = 0.0f;
    #pragma unroll
    for (int c = 0; c < 64; c += 4) {
        float4 a  = *(const float4*)(featp + b00 + c);
        float4 b_ = *(const float4*)(featp + b01 + c);
        float4 g  = *(const float4*)(featp + b10 + c);
        float4 d  = *(const float4*)(featp + b11 + c);
        float e0 = a.x * w00 + b_.x * w01 + g.x * w10 + d.x * w11;
        float e1 = a.y * w00 + b_.y * w01 + g.y * w10 + d.y * w11;
        float e2 = a.z * w00 + b_.z * w01 + g.z * w10 + d.z * w11;
        float e3 = a.w * w00 + b_.w * w01 + g.w * w10 + d.w * w11;
        fr[c] = e0; fr[c+1] = e1; fr[c+2] = e2; fr[c+3] = e3;
        ss += e0*e0; ss += e1*e1; ss += e2*e2; ss += e3*e3;
    }
    float inv = 1.0f / fmaxf(sqrtf(ss), 1e-12f);
    #pragma unroll
    for (int c = 0; c < 64; c += 4) {
        *(float4*)(cn + ob + c) =
            make_float4(fr[c]*inv, fr[c+1]*inv, fr[c+2]*inv, fr[c+3]*inv);
    }
    #pragma unroll
    for (int c = 0; c < 64; c += 4) {
        float4 a  = *(const float4*)(valp + b00 + c);
        float4 b_ = *(const float4*)(valp + b01 + c);
        float4 g  = *(const float4*)(valp + b10 + c);
        float4 d  = *(const float4*)(valp + b11 + c);
        float4 o;
        o.x = a.x * w00 + b_.x * w01 + g.x * w10 + d.x * w11;
        o.y = a.y * w00 + b_.y * w01 + g.y * w10 + d.y * w11;
        o.z = a.z * w00 + b_.z * w01 + g.z * w10 + d.z * w11;
        o.w = a.w * w00 + b_.w * w01 + g.w * w10 + d.w * w11;
        *(float4*)(vc + ob + c) = o;
    }
}

// ---------------------------------------------------------------------------
// K4a v3: cosine-sim running argmax, one 128-key x 256-center tile per block.
// 16(centers) x 8(keys) per-thread register blocking; channel-major LDS.
// Per-thread key fragment split into two float4 groups (cols tx*4 and 64+tx*4)
// so B-reads are 2-way bank-aliased (free) instead of 4-way.
// Grid (KT2, SPLITS, 4) x 256. LDS 96 KiB -> 1 block/CU.
// ---------------------------------------------------------------------------
__global__ __launch_bounds__(256, 1) void k4a_sim(
    const float* __restrict__ featp, const float* __restrict__ invn,
    const float* __restrict__ cn, const int* __restrict__ counts,
    const float* __restrict__ alpha_p, const float* __restrict__ beta_p,
    float* __restrict__ part_s, int* __restrict__ part_m)
{
    __shared__ float At[64 * CTILE];   // [ch][center]  64 KiB
    __shared__ float Bt[64 * 128];     // [ch][key]     32 KiB

    int r     = blockIdx.z;
    int kt    = blockIdx.x;
    int split = blockIdx.y;
    int k0 = kt * 128;
    int t  = threadIdx.x;
    int tx = t & 15, ty = t >> 4;      // tx -> 8 keys (2 groups of 4), ty -> 16 centers
    int K  = counts[r];
    int Mr = min(K + 1, MCAP);
    float alpha = alpha_p[0], beta = beta_p[0];

    int ntiles = (Mr + CTILE - 1) / CTILE;           // <= 9 for MCAP-bounded Mr
    int ct0 = (split * ntiles) / SPLITS;             // even distribution
    int ct1 = ((split + 1) * ntiles) / SPLITS;       // 0 or 1 tiles per block

    float best_s[8];
    int   best_m[8];
    #pragma unroll
    for (int v = 0; v < 8; v++) { best_s[v] = -INFINITY; best_m[v] = INT_MAX; }

    if (ct0 < ct1) {
        // stage B tile: 128 keys x 64 ch, normalized, channel-major
        {
            int j = t >> 1, hh = (t & 1) * 32;
            float inv = invn[r * QPIX + k0 + j];
            const float* src = featp + ((size_t)(r * QPIX + k0 + j)) * 64 + hh;
            #pragma unroll
            for (int i = 0; i < 32; i += 4) {
                float4 fv = *(const float4*)(src + i);
                Bt[(hh + i + 0) * 128 + j] = fv.x * inv;
                Bt[(hh + i + 1) * 128 + j] = fv.y * inv;
                Bt[(hh + i + 2) * 128 + j] = fv.z * inv;
                Bt[(hh + i + 3) * 128 + j] = fv.w * inv;
            }
        }
        // stage A tile: 256 centers x 64 ch, channel-major (thread = center)
        {
            int mg = min(ct0 * CTILE + t, MCAP - 1);
            const float* src = cn + ((size_t)(r * MCAP + mg)) * 64;
            #pragma unroll
            for (int c = 0; c < 64; c += 4) {
                float4 fv = *(const float4*)(src + c);
                At[(c + 0) * CTILE + t] = fv.x;
                At[(c + 1) * CTILE + t] = fv.y;
                At[(c + 2) * CTILE + t] = fv.z;
                At[(c + 3) * CTILE + t] = fv.w;
            }
        }
        __syncthreads();

        float dot[16][8] = {};
        #pragma unroll 4
        for (int cc = 0; cc < 64; cc++) {
            const float* Ar = At + cc * CTILE + ty * 16;
            float4 a0 = *(const float4*)(Ar + 0);
            float4 a1 = *(const float4*)(Ar + 4);
            float4 a2 = *(const float4*)(Ar + 8);
            float4 a3 = *(const float4*)(Ar + 12);
            float4 b0 = *(const float4*)(Bt + cc * 128 + tx * 4);
            float4 b1 = *(const float4*)(Bt + cc * 128 + 64 + tx * 4);
            float a[16] = {a0.x,a0.y,a0.z,a0.w, a1.x,a1.y,a1.z,a1.w,
                           a2.x,a2.y,a2.z,a2.w, a3.x,a3.y,a3.z,a3.w};
            float b[8]  = {b0.x,b0.y,b0.z,b0.w, b1.x,b1.y,b1.z,b1.w};
            #pragma unroll
            for (int u = 0; u < 16; u++) {
                #pragma unroll
                for (int v = 0; v < 8; v++)
                    dot[u][v] = fmaf(a[u], b[v], dot[u][v]);
            }
        }
        // running argmax; m ascending within thread (u ascending); strict >
        // keeps smallest m on exact fp32 ties (reference first-max rule)
        #pragma unroll
        for (int u = 0; u < 16; u++) {
            int mg = ct0 * CTILE + ty * 16 + u;
            bool valid = mg < Mr;
            #pragma unroll
            for (int v = 0; v < 8; v++) {
                float s = fmaf(alpha, dot[u][v], beta);  // monotone w/ sigmoid
                if (valid && s > best_s[v]) { best_s[v] = s; best_m[v] = mg; }
            }
        }
    }

    // cross-thread (ty) reduce per key; tie -> smaller m; store partials.
    // Reuse Bt as [16][128] scratch after all compute reads are done.
    __syncthreads();
    float* rs = Bt;
    int*   rm = (int*)(Bt + 2048);
    #pragma unroll
    for (int v = 0; v < 8; v++) {
        int col = tx * 4 + (v & 3) + ((v >> 2) << 6);   // key column this best belongs to
        rs[ty * 128 + col] = best_s[v];
        rm[ty * 128 + col] = best_m[v];
    }
    __syncthreads();
    if (t < 128) {
        float bs = rs[t]; int bm = rm[t];
        #pragma unroll
        for (int y = 1; y < 16; y++) {
            float s2 = rs[y * 128 + t]; int m2 = rm[y * 128 + t];
            if (s2 > bs || (s2 == bs && m2 < bm)) { bs = s2; bm = m2; }
        }
        size_t pb = ((size_t)((r * KT2 + kt) * SPLITS + split)) * 128;
        part_s[pb + t] = bs;
        part_m[pb + t] = bm;
    }
}

// ---------------------------------------------------------------------------
// K4b: reduce split partials per key (tie -> smaller m), sigmoid, scatter.
// Grid (KTILES, 4) x 256; 4 threads per key, 16 channels each.
// ---------------------------------------------------------------------------
__global__ __launch_bounds__(256) void k4b_scatter(
    const float* __restrict__ part_s, const int* __restrict__ part_m,
    const float* __restrict__ valp, const int* __restrict__ counts,
    float* __restrict__ agg, float* __restrict__ denom)
{
    int r  = blockIdx.y;
    int t  = threadIdx.x;
    int j = t >> 2, cq = (t & 3) * 16;
    int gk = blockIdx.x * 64 + j;       // global key 0..3455
    int kt = gk >> 7, jj = gk & 127;    // k4a 128-key tile / offset
    int K = counts[r];

    size_t pb = ((size_t)((r * KT2 + kt) * SPLITS)) * 128;
    float bs = -INFINITY; int bm = INT_MAX;
    #pragma unroll
    for (int s = 0; s < SPLITS; s++) {
        float s2 = part_s[pb + (size_t)s * 128 + jj];
        int   m2 = part_m[pb + (size_t)s * 128 + jj];
        if (s2 > bs || (s2 == bs && m2 < bm)) { bs = s2; bm = m2; }
    }
    if (bm < K) {   // skip phantom / empty winners
        float wgt = 1.0f / (1.0f + expf(-bs));
        float* ad = agg + ((size_t)(r * MCAP + bm)) * 64 + cq;
        const float* vsrc = valp + ((size_t)(r * QPIX + gk)) * 64 + cq;
        #pragma unroll
        for (int i = 0; i < 16; i++) atomicAdd(ad + i, wgt * vsrc[i]);
        if ((t & 3) == 0) atomicAdd(denom + r * MCAP + bm, wgt);
    }
}

// ---------------------------------------------------------------------------
// K5: per-point output + projection + transposed store [1,64,1,8192]
// ---------------------------------------------------------------------------
__global__ __launch_bounds__(256) void k5_out(
    const float* __restrict__ agg, const float* __restrict__ vc,
    const float* __restrict__ denom, const int* __restrict__ slot,
    const float* __restrict__ Wp, const float* __restrict__ bp,
    float* __restrict__ out)
{
    __shared__ float WT[64 * 65];
    __shared__ float ov[4][64];
    __shared__ float res[4][64];
    int t = threadIdx.x;
    {
        int o = t >> 2, cq = (t & 3) * 16;
        #pragma unroll
        for (int i = 0; i < 16; i += 4) {
            float4 wv = *(const float4*)(Wp + o * 64 + cq + i);
            WT[(cq + i + 0) * 65 + o] = wv.x;
            WT[(cq + i + 1) * 65 + o] = wv.y;
            WT[(cq + i + 2) * 65 + o] = wv.z;
            WT[(cq + i + 3) * 65 + o] = wv.w;
        }
    }
    int p = t >> 6, c = t & 63;
    int n = blockIdx.x * 4 + p;
    int sl = slot[n];
    float d = denom[sl] + 1.0f;
    float o_v = (agg[(size_t)sl * 64 + c] + vc[(size_t)sl * 64 + c]) / d;
    ov[p][c] = o_v;
    unsigned long long nz = __ballot(o_v != 0.0f);   // wave == point
    __syncthreads();
    float acc = bp[c];
    #pragma unroll
    for (int cc = 0; cc < 64; cc++)
        acc = fmaf(ov[p][cc], WT[cc * 65 + c], acc);
    res[p][c] = (nz != 0ull) ? acc : 0.0f;
    __syncthreads();
    if (t < 64) {
        float4 val = make_float4(res[0][t], res[1][t], res[2][t], res[3][t]);
        *(float4*)(out + (size_t)t * NPTS + blockIdx.x * 4) = val;
    }
}

// ---------------------------------------------------------------------------
extern "C" void kernel_launch(void* const* d_in, const int* in_sizes, int n_in,
                              void* d_out, int out_size, void* d_ws, size_t ws_size,
                              hipStream_t stream) {
    const float* points = (const float*)d_in[0];
    const float* x      = (const float*)d_in[1];
    const float* Wf     = (const float*)d_in[2];
    const float* bf     = (const float*)d_in[3];
    const float* Wv     = (const float*)d_in[4];
    const float* bv     = (const float*)d_in[5];
    const float* Wp     = (const float*)d_in[6];
    const float* bp     = (const float*)d_in[7];
    const float* alpha  = (const float*)d_in[8];
    const float* beta   = (const float*)d_in[9];
    float* out = (float*)d_out;

    float* ws    = (float*)d_ws;
    float* featp = ws;                        // 884736
    float* valp  = featp + 884736;            // 884736
    float* cn    = valp  + 884736;            // 786432 (4*MCAP*64)
    float* vc    = cn    + 786432;            // 786432
    float* agg   = vc    + 786432;            // 786432
    float* denom = agg   + 786432;            // 12288 (4*MCAP)
    float* invn  = denom + 12288;             // 13824
    float* cp    = invn  + 13824;             // 24576 (2*4*MCAP)
    float* part_s= cp    + 24576;             // 124416 (4*27*9*128)
    int*   part_m= (int*)(part_s + 124416);   // 124416
    int*   ccnt  = part_m + 124416;           // 512
    int*   cbase = ccnt   + 512;              // 512
    int*   counts= cbase  + 512;              // 16
    int*   slot  = counts + 16;               // 8192
    // total ~17.8 MB of d_ws

    // agg + denom must start at zero (ws is poisoned every launch)
    hipMemsetAsync(agg, 0, (size_t)(786432 + 12288) * sizeof(float), stream);

    k1_linmaps<<<216, 256, 0, stream>>>(x, Wf, bf, Wv, bv, featp, valp, invn);
    k2a_count  <<<128, 64, 0, stream>>>(points, ccnt);
    k2b_scan   <<<1, 256, 0, stream>>>(ccnt, cbase, counts);
    k2c_scatter<<<128, 64, 0, stream>>>(points, cbase, cp, slot);
    k3_gather<<<dim3(MCAP / 64, 4), 64, 0, stream>>>(featp, valp, cp, counts, cn, vc);
    k4a_sim<<<dim3(KT2, SPLITS, 4), 256, 0, stream>>>(featp, invn, cn, counts,
                                                      alpha, beta, part_s, part_m);
    k4b_scatter<<<dim3(KTILES, 4), 256, 0, stream>>>(part_s, part_m, valp, counts,
                                                     agg, denom);
    k5_out<<<NPTS / 4, 256, 0, stream>>>(agg, vc, denom, slot, Wp, bp, out);
}

// Round 3
// 257.338 us; speedup vs baseline: 1.0623x; 1.0623x over previous
//
#include <hip/hip_runtime.h>
#include <math.h>
#include <float.h>
#include <limits.h>

// Problem constants
#define PIX    13824   // 64*216
#define QPIX   3456    // 32*108
#define QW     108
#define QH     32
#define NPTS   8192
#define MCAP   3072    // per-quadrant center capacity (expected ~2048, 26 sigma)
#define KTILES 54      // QPIX/64  (k4b key-groups)
#define KT2    27      // QPIX/128 (k4a key tiles)
#define CSPL   24      // center-splits: each handles 2 x 64-center tiles (covers MCAP)

// ---------------------------------------------------------------------------
// K1: feat/value linear maps + fold to [r][k][c] pixel-major + feat inv-norm.
// Also zeroes agg+denom (k4b accumulators) - replaces the memset dispatch.
// ---------------------------------------------------------------------------
__global__ __launch_bounds__(256) void k1_linmaps(
    const float* __restrict__ x, const float* __restrict__ Wf, const float* __restrict__ bf,
    const float* __restrict__ Wv, const float* __restrict__ bv,
    float* __restrict__ featp, float* __restrict__ valp, float* __restrict__ invn,
    float* __restrict__ aggz)
{
    __shared__ float ssq[4][64];
    int t = threadIdx.x;

    // zero agg(786432) + denom(12288) = 798720 floats = 199680 float4
    {
        float4 z4 = make_float4(0.f, 0.f, 0.f, 0.f);
        for (int i = blockIdx.x * 256 + t; i < 199680; i += 216 * 256)
            ((float4*)aggz)[i] = z4;
    }

    int lane = t & 63;
    int q = t >> 6;                       // wave id -> o-group (wave-uniform)
    int pix = blockIdx.x * 64 + lane;     // 216*64 = 13824 exact
    int h = pix / 216;
    int w = pix - h * 216;
    int r = ((h >> 5) << 1) | (w >= QW ? 1 : 0);
    int k = (h & 31) * QW + (w >= QW ? w - QW : w);

    float xr[64];
    #pragma unroll
    for (int c = 0; c < 64; c++) xr[c] = x[c * PIX + pix];

    size_t base = ((size_t)(r * QPIX + k)) * 64 + q * 16;
    float ss = 0.0f;
    for (int i = 0; i < 16; i++) {
        int o = q * 16 + i;               // wave-uniform
        float af = bf[o], av = bv[o];
        #pragma unroll
        for (int c = 0; c < 64; c++) {
            af = fmaf(Wf[o * 64 + c], xr[c], af);
            av = fmaf(Wv[o * 64 + c], xr[c], av);
        }
        featp[base + i] = af;
        valp[base + i]  = av;
        ss += af * af;
    }
    ssq[q][lane] = ss;
    __syncthreads();
    if (q == 0) {
        float tot = ssq[0][lane] + ssq[1][lane] + ssq[2][lane] + ssq[3][lane];
        invn[r * QPIX + k] = 1.0f / fmaxf(sqrtf(tot), 1e-12f);
    }
}

// ---------------------------------------------------------------------------
// K2 (order-preserving compaction), now 2 dispatches:
//   k2a: per-64-point-chunk quadrant counts (128 chunks)
//   k2c: per-block redundant scan of chunk counts + ranked scatter
// ---------------------------------------------------------------------------
__device__ __forceinline__ int point_quadrant(float px, float py) {
    // rh = 384/2 = 192 exact, rw = 1296/2 = 648 exact
    return ((py > 192.0f) ? 2 : 0) + ((px > 648.0f) ? 1 : 0);
}

__global__ __launch_bounds__(64) void k2a_count(
    const float* __restrict__ points, int* __restrict__ ccnt)
{
    int lane = threadIdx.x;
    int chunk = blockIdx.x;
    float2 p = ((const float2*)points)[chunk * 64 + lane];
    int q = point_quadrant(p.x, p.y);
    #pragma unroll
    for (int r = 0; r < 4; r++) {
        unsigned long long m = __ballot(q == r);
        if (lane == 0) ccnt[chunk * 4 + r] = __popcll(m);
    }
}

__global__ __launch_bounds__(64) void k2c_scatter(
    const float* __restrict__ points, const int* __restrict__ ccnt,
    float* __restrict__ cp, int* __restrict__ slot, int* __restrict__ counts)
{
    int lane = threadIdx.x;
    int chunk = blockIdx.x;

    // redundant per-block scan: prefix over chunks < my chunk, per quadrant
    int c0[4], c1[4], pre[4];
    #pragma unroll
    for (int r = 0; r < 4; r++) {
        c0[r] = ccnt[lane * 4 + r];
        c1[r] = ccnt[(lane + 64) * 4 + r];
        pre[r] = (lane < chunk ? c0[r] : 0) + (lane + 64 < chunk ? c1[r] : 0);
    }
    #pragma unroll
    for (int d = 1; d < 64; d <<= 1) {
        #pragma unroll
        for (int r = 0; r < 4; r++) pre[r] += __shfl_xor(pre[r], d, 64);
    }
    if (chunk == 0) {   // block 0 also publishes the totals
        int full[4];
        #pragma unroll
        for (int r = 0; r < 4; r++) full[r] = c0[r] + c1[r];
        #pragma unroll
        for (int d = 1; d < 64; d <<= 1) {
            #pragma unroll
            for (int r = 0; r < 4; r++) full[r] += __shfl_xor(full[r], d, 64);
        }
        if (lane == 0) {
            #pragma unroll
            for (int r = 0; r < 4; r++) counts[r] = full[r];
        }
    }

    int n = chunk * 64 + lane;
    float2 p = ((const float2*)points)[n];
    int q = point_quadrant(p.x, p.y);
    unsigned long long below = (lane == 0) ? 0ull : (~0ull >> (64 - lane));
    #pragma unroll
    for (int r = 0; r < 4; r++) {
        unsigned long long m = __ballot(q == r);
        if (q == r) {
            int pos = pre[r] + __popcll(m & below);
            ((float2*)cp)[r * MCAP + pos] = p;
            slot[n] = r * MCAP + pos;
        }
    }
}

// ---------------------------------------------------------------------------
// K3: bilinear gather (border clamp) of feat & value at compacted points;
// slot m == K_r is the phantom (0,0) padded row.
// ---------------------------------------------------------------------------
__global__ __launch_bounds__(64) void k3_gather(
    const float* __restrict__ featp, const float* __restrict__ valp,
    const float* __restrict__ cp, const int* __restrict__ counts,
    float* __restrict__ cn, float* __restrict__ vc)
{
    int r = blockIdx.y;
    int m = blockIdx.x * 64 + threadIdx.x;
    int K = counts[r];
    int Mr = min(K + 1, MCAP);
    if (m >= Mr) return;
    float px = 0.0f, py = 0.0f;
    if (m < K) { float2 p = ((const float2*)cp)[r * MCAP + m]; px = p.x; py = p.y; }

    // mirror reference op order: grid = p/(S-1)*2-1 ; g = (grid+1)*(D/2)-0.5
    float gx = (px / 1295.0f * 2.0f - 1.0f + 1.0f) * 54.0f - 0.5f;
    float gy = (py / 383.0f  * 2.0f - 1.0f + 1.0f) * 16.0f - 0.5f;
    float x0 = floorf(gx), y0 = floorf(gy);
    float wx = gx - x0, wy = gy - y0;
    int x0i = (int)fminf(fmaxf(x0,         0.0f), 107.0f);
    int x1i = (int)fminf(fmaxf(x0 + 1.0f,  0.0f), 107.0f);
    int y0i = (int)fminf(fmaxf(y0,         0.0f), 31.0f);
    int y1i = (int)fminf(fmaxf(y0 + 1.0f,  0.0f), 31.0f);
    float w00 = (1.0f - wx) * (1.0f - wy);
    float w01 = wx * (1.0f - wy);
    float w10 = (1.0f - wx) * wy;
    float w11 = wx * wy;

    size_t b00 = ((size_t)(r * QPIX + y0i * QW + x0i)) * 64;
    size_t b01 = ((size_t)(r * QPIX + y0i * QW + x1i)) * 64;
    size_t b10 = ((size_t)(r * QPIX + y1i * QW + x0i)) * 64;
    size_t b11 = ((size_t)(r * QPIX + y1i * QW + x1i)) * 64;
    size_t ob  = ((size_t)(r * MCAP + m)) * 64;

    float fr[64];
    float ss = 0.0f;
    #pragma unroll
    for (int c = 0; c < 64; c += 4) {
        float4 a  = *(const float4*)(featp + b00 + c);
        float4 b_ = *(const float4*)(featp + b01 + c);
        float4 g  = *(const float4*)(featp + b10 + c);
        float4 d  = *(const float4*)(featp + b11 + c);
        float e0 = a.x * w00 + b_.x * w01 + g.x * w10 + d.x * w11;
        float e1 = a.y * w00 + b_.y * w01 + g.y * w10 + d.y * w11;
        float e2 = a.z * w00 + b_.z * w01 + g.z * w10 + d.z * w11;
        float e3 = a.w * w00 + b_.w * w01 + g.w * w10 + d.w * w11;
        fr[c] = e0; fr[c+1] = e1; fr[c+2] = e2; fr[c+3] = e3;
        ss += e0*e0; ss += e1*e1; ss += e2*e2; ss += e3*e3;
    }
    float inv = 1.0f / fmaxf(sqrtf(ss), 1e-12f);
    #pragma unroll
    for (int c = 0; c < 64; c += 4) {
        *(float4*)(cn + ob + c) =
            make_float4(fr[c]*inv, fr[c+1]*inv, fr[c+2]*inv, fr[c+3]*inv);
    }
    #pragma unroll
    for (int c = 0; c < 64; c += 4) {
        float4 a  = *(const float4*)(valp + b00 + c);
        float4 b_ = *(const float4*)(valp + b01 + c);
        float4 g  = *(const float4*)(valp + b10 + c);
        float4 d  = *(const float4*)(valp + b11 + c);
        float4 o;
        o.x = a.x * w00 + b_.x * w01 + g.x * w10 + d.x * w11;
        o.y = a.y * w00 + b_.y * w01 + g.y * w10 + d.y * w11;
        o.z = a.z * w00 + b_.z * w01 + g.z * w10 + d.z * w11;
        o.w = a.w * w00 + b_.w * w01 + g.w * w10 + d.w * w11;
        *(float4*)(vc + ob + c) = o;
    }
}

// ---------------------------------------------------------------------------
// K4a v4: cosine-sim running argmax. 128 keys x 64 centers per tile, 2 tiles
// per block. Frag 8 keys x 4 centers. LDS 48 KiB (Bt 32K ch-major + At 16K
// ch-major) -> 3 blocks/CU; cross-block overlap hides staging latency.
// All LDS reads <=2-way bank aliased (free). Grid (KT2, CSPL, 4) x 256.
// ---------------------------------------------------------------------------
__global__ __launch_bounds__(256) void k4a_sim(
    const float* __restrict__ featp, const float* __restrict__ invn,
    const float* __restrict__ cn, const int* __restrict__ counts,
    const float* __restrict__ alpha_p, const float* __restrict__ beta_p,
    float* __restrict__ part_s, int* __restrict__ part_m)
{
    __shared__ float Bt[64 * 128];   // [ch][key]     32 KiB
    __shared__ float At[64 * 64];    // [ch][center]  16 KiB

    int r  = blockIdx.z;
    int kt = blockIdx.x;
    int sp = blockIdx.y;
    int k0 = kt * 128;
    int t  = threadIdx.x;
    int tx = t & 15, ty = t >> 4;    // tx -> 8 keys (2 groups of 4), ty -> 4 centers
    int K  = counts[r];
    int Mr = min(K + 1, MCAP);
    int ntiles = (Mr + 63) >> 6;
    int ct0 = sp * 2;
    if (ct0 >= ntiles) return;       // k4b only reads partials for s < ceil(ntiles/2)
    int ctEnd = min(ct0 + 2, ntiles);
    float alpha = alpha_p[0], beta = beta_p[0];

    // stage B tile: 128 keys x 64 ch, normalized, channel-major
    {
        int j = t >> 1, hh = (t & 1) * 32;
        float inv = invn[r * QPIX + k0 + j];
        const float* src = featp + ((size_t)(r * QPIX + k0 + j)) * 64 + hh;
        #pragma unroll
        for (int i = 0; i < 32; i += 4) {
            float4 fv = *(const float4*)(src + i);
            Bt[(hh + i + 0) * 128 + j] = fv.x * inv;
            Bt[(hh + i + 1) * 128 + j] = fv.y * inv;
            Bt[(hh + i + 2) * 128 + j] = fv.z * inv;
            Bt[(hh + i + 3) * 128 + j] = fv.w * inv;
        }
    }

    float best_s[8];
    int   best_m[8];
    #pragma unroll
    for (int v = 0; v < 8; v++) { best_s[v] = -INFINITY; best_m[v] = INT_MAX; }

    int aj = t & 63, ack = (t >> 6) * 16;   // A-staging: center row / ch-chunk
    for (int ct = ct0; ct < ctEnd; ct++) {
        // load A sub-tile (64 centers x 16 ch per thread-group) to registers
        float4 pf[4];
        {
            int mg = min(ct * 64 + aj, MCAP - 1);
            const float* src = cn + ((size_t)(r * MCAP + mg)) * 64 + ack;
            #pragma unroll
            for (int i = 0; i < 4; i++) pf[i] = *(const float4*)(src + i * 4);
        }
        if (ct > ct0) __syncthreads();      // prior tile's At reads done
        #pragma unroll
        for (int i = 0; i < 4; i++) {
            At[(ack + i * 4 + 0) * 64 + aj] = pf[i].x;
            At[(ack + i * 4 + 1) * 64 + aj] = pf[i].y;
            At[(ack + i * 4 + 2) * 64 + aj] = pf[i].z;
            At[(ack + i * 4 + 3) * 64 + aj] = pf[i].w;
        }
        __syncthreads();                    // (1st iter: also covers Bt writes)

        float dot[4][8] = {};
        #pragma unroll 4
        for (int cc = 0; cc < 64; cc++) {
            float4 a0 = *(const float4*)(At + cc * 64 + ty * 4);
            float4 b0 = *(const float4*)(Bt + cc * 128 + tx * 4);
            float4 b1 = *(const float4*)(Bt + cc * 128 + 64 + tx * 4);
            float a[4] = {a0.x, a0.y, a0.z, a0.w};
            float b[8] = {b0.x, b0.y, b0.z, b0.w, b1.x, b1.y, b1.z, b1.w};
            #pragma unroll
            for (int u = 0; u < 4; u++) {
                #pragma unroll
                for (int v = 0; v < 8; v++)
                    dot[u][v] = fmaf(a[u], b[v], dot[u][v]);
            }
        }
        // running argmax; m ascending (ct, then u); strict > keeps smallest m
        // on exact fp32 ties (reference first-max rule)
        #pragma unroll
        for (int u = 0; u < 4; u++) {
            int mg = ct * 64 + ty * 4 + u;
            bool valid = mg < Mr;
            #pragma unroll
            for (int v = 0; v < 8; v++) {
                float s = fmaf(alpha, dot[u][v], beta);  // monotone w/ sigmoid
                if (valid && s > best_s[v]) { best_s[v] = s; best_m[v] = mg; }
            }
        }
    }

    // cross-thread (ty) reduce per key; tie -> smaller m; store partials.
    // Reuse Bt as [16][128] scratch after all compute reads are done.
    __syncthreads();
    float* rs = Bt;
    int*   rm = (int*)(Bt + 2048);
    #pragma unroll
    for (int v = 0; v < 8; v++) {
        int col = tx * 4 + (v & 3) + ((v >> 2) << 6);   // key column of this best
        rs[ty * 128 + col] = best_s[v];
        rm[ty * 128 + col] = best_m[v];
    }
    __syncthreads();
    if (t < 128) {
        float bs = rs[t]; int bm = rm[t];
        #pragma unroll
        for (int y = 1; y < 16; y++) {
            float s2 = rs[y * 128 + t]; int m2 = rm[y * 128 + t];
            if (s2 > bs || (s2 == bs && m2 < bm)) { bs = s2; bm = m2; }
        }
        size_t pb = ((size_t)((r * KT2 + kt) * CSPL + sp)) * 128;
        part_s[pb + t] = bs;
        part_m[pb + t] = bm;
    }
}

// ---------------------------------------------------------------------------
// K4b: reduce split partials per key (tie -> smaller m), sigmoid, scatter.
// Grid (KTILES, 4) x 256; 4 threads per key, 16 channels each.
// ---------------------------------------------------------------------------
__global__ __launch_bounds__(256) void k4b_scatter(
    const float* __restrict__ part_s, const int* __restrict__ part_m,
    const float* __restrict__ valp, const int* __restrict__ counts,
    float* __restrict__ agg, float* __restrict__ denom)
{
    int r  = blockIdx.y;
    int t  = threadIdx.x;
    int j = t >> 2, cq = (t & 3) * 16;
    int gk = blockIdx.x * 64 + j;       // global key 0..3455
    int kt = gk >> 7, jj = gk & 127;    // k4a 128-key tile / offset
    int K = counts[r];
    int Mr = min(K + 1, MCAP);
    int nS = (((Mr + 63) >> 6) + 1) >> 1;   // active splits

    size_t pb = ((size_t)((r * KT2 + kt) * CSPL)) * 128;
    float bs = -INFINITY; int bm = INT_MAX;
    for (int s = 0; s < nS; s++) {
        float s2 = part_s[pb + (size_t)s * 128 + jj];
        int   m2 = part_m[pb + (size_t)s * 128 + jj];
        if (s2 > bs || (s2 == bs && m2 < bm)) { bs = s2; bm = m2; }
    }
    if (bm < K) {   // skip phantom / empty winners
        float wgt = 1.0f / (1.0f + expf(-bs));
        float* ad = agg + ((size_t)(r * MCAP + bm)) * 64 + cq;
        const float* vsrc = valp + ((size_t)(r * QPIX + gk)) * 64 + cq;
        #pragma unroll
        for (int i = 0; i < 16; i++) atomicAdd(ad + i, wgt * vsrc[i]);
        if ((t & 3) == 0) atomicAdd(denom + r * MCAP + bm, wgt);
    }
}

// ---------------------------------------------------------------------------
// K5: per-point output + projection + transposed store [1,64,1,8192].
// 32 points per block (8 passes of 4) so Wp is staged once per block.
// ---------------------------------------------------------------------------
__global__ __launch_bounds__(256) void k5_out(
    const float* __restrict__ agg, const float* __restrict__ vc,
    const float* __restrict__ denom, const int* __restrict__ slot,
    const float* __restrict__ Wp, const float* __restrict__ bp,
    float* __restrict__ out)
{
    __shared__ float WT[64 * 65];
    __shared__ float ov[4][68];
    __shared__ float res[4][64];
    int t = threadIdx.x;
    {
        int o = t >> 2, cq = (t & 3) * 16;
        #pragma unroll
        for (int i = 0; i < 16; i += 4) {
            float4 wv = *(const float4*)(Wp + o * 64 + cq + i);
            WT[(cq + i + 0) * 65 + o] = wv.x;
            WT[(cq + i + 1) * 65 + o] = wv.y;
            WT[(cq + i + 2) * 65 + o] = wv.z;
            WT[(cq + i + 3) * 65 + o] = wv.w;
        }
    }
    int p = t >> 6, c = t & 63;
    for (int pp = 0; pp < 8; pp++) {
        int n = blockIdx.x * 32 + pp * 4 + p;
        int sl = slot[n];
        float d = denom[sl] + 1.0f;
        float o_v = (agg[(size_t)sl * 64 + c] + vc[(size_t)sl * 64 + c]) / d;
        ov[p][c] = o_v;
        unsigned long long nz = __ballot(o_v != 0.0f);   // wave == point
        __syncthreads();   // ov ready (1st iter: also covers WT staging)
        float acc = bp[c];
        #pragma unroll
        for (int cc = 0; cc < 64; cc++)
            acc = fmaf(ov[p][cc], WT[cc * 65 + c], acc);
        res[p][c] = (nz != 0ull) ? acc : 0.0f;
        __syncthreads();   // res ready; ov reads done before next-pass writes
        if (t < 64) {
            float4 val = make_float4(res[0][t], res[1][t], res[2][t], res[3][t]);
            *(float4*)(out + (size_t)t * NPTS + blockIdx.x * 32 + pp * 4) = val;
        }
    }
}

// ---------------------------------------------------------------------------
extern "C" void kernel_launch(void* const* d_in, const int* in_sizes, int n_in,
                              void* d_out, int out_size, void* d_ws, size_t ws_size,
                              hipStream_t stream) {
    const float* points = (const float*)d_in[0];
    const float* x      = (const float*)d_in[1];
    const float* Wf     = (const float*)d_in[2];
    const float* bf     = (const float*)d_in[3];
    const float* Wv     = (const float*)d_in[4];
    const float* bv     = (const float*)d_in[5];
    const float* Wp     = (const float*)d_in[6];
    const float* bp     = (const float*)d_in[7];
    const float* alpha  = (const float*)d_in[8];
    const float* beta   = (const float*)d_in[9];
    float* out = (float*)d_out;

    float* ws    = (float*)d_ws;
    float* featp = ws;                        // 884736
    float* valp  = featp + 884736;            // 884736
    float* cn    = valp  + 884736;            // 786432 (4*MCAP*64)
    float* vc    = cn    + 786432;            // 786432
    float* agg   = vc    + 786432;            // 786432  (zeroed by k1)
    float* denom = agg   + 786432;            // 12288 (4*MCAP, zeroed by k1)
    float* invn  = denom + 12288;             // 13824
    float* cp    = invn  + 13824;             // 24576 (2*4*MCAP)
    float* part_s= cp    + 24576;             // 331776 (4*27*24*128)
    int*   part_m= (int*)(part_s + 331776);   // 331776
    int*   ccnt  = part_m + 331776;           // 512
    int*   counts= ccnt   + 512;              // 16
    int*   slot  = counts + 16;               // 8192
    // total ~19.4 MB of d_ws

    k1_linmaps<<<216, 256, 0, stream>>>(x, Wf, bf, Wv, bv, featp, valp, invn, agg);
    k2a_count  <<<128, 64, 0, stream>>>(points, ccnt);
    k2c_scatter<<<128, 64, 0, stream>>>(points, ccnt, cp, slot, counts);
    k3_gather<<<dim3(MCAP / 64, 4), 64, 0, stream>>>(featp, valp, cp, counts, cn, vc);
    k4a_sim<<<dim3(KT2, CSPL, 4), 256, 0, stream>>>(featp, invn, cn, counts,
                                                    alpha, beta, part_s, part_m);
    k4b_scatter<<<dim3(KTILES, 4), 256, 0, stream>>>(part_s, part_m, valp, counts,
                                                     agg, denom);
    k5_out<<<NPTS / 32, 256, 0, stream>>>(agg, vc, denom, slot, Wp, bp, out);
}

// Round 4
// 206.269 us; speedup vs baseline: 1.3253x; 1.2476x over previous
//
#include <hip/hip_runtime.h>
#include <math.h>
#include <float.h>
#include <limits.h>

// Problem constants
#define PIX    13824   // 64*216
#define QPIX   3456    // 32*108
#define QW     108
#define QH     32
#define NPTS   8192
#define MCAP   3072    // per-quadrant center capacity (expected ~2048, 26 sigma)
#define KT2    27      // QPIX/128 (k4a key tiles)
#define CSPL   24      // center-splits: each handles 2 x 64-center tiles (covers MCAP)

// ---------------------------------------------------------------------------
// K1: feat/value linear maps + fold to [r][k][c] pixel-major + feat inv-norm.
// Also zeroes agg+denom+cnt (aggregation state) - no separate memset dispatch.
// ---------------------------------------------------------------------------
__global__ __launch_bounds__(256) void k1_linmaps(
    const float* __restrict__ x, const float* __restrict__ Wf, const float* __restrict__ bf,
    const float* __restrict__ Wv, const float* __restrict__ bv,
    float* __restrict__ featp, float* __restrict__ valp, float* __restrict__ invn,
    float* __restrict__ aggz)
{
    __shared__ float ssq[4][64];
    int t = threadIdx.x;

    // zero agg(786432) + denom(12288) + cnt(12288) = 811008 floats = 202752 float4
    {
        float4 z4 = make_float4(0.f, 0.f, 0.f, 0.f);
        for (int i = blockIdx.x * 256 + t; i < 202752; i += 216 * 256)
            ((float4*)aggz)[i] = z4;
    }

    int lane = t & 63;
    int q = t >> 6;                       // wave id -> o-group (wave-uniform)
    int pix = blockIdx.x * 64 + lane;     // 216*64 = 13824 exact
    int h = pix / 216;
    int w = pix - h * 216;
    int r = ((h >> 5) << 1) | (w >= QW ? 1 : 0);
    int k = (h & 31) * QW + (w >= QW ? w - QW : w);

    float xr[64];
    #pragma unroll
    for (int c = 0; c < 64; c++) xr[c] = x[c * PIX + pix];

    size_t base = ((size_t)(r * QPIX + k)) * 64 + q * 16;
    float ss = 0.0f;
    for (int i = 0; i < 16; i++) {
        int o = q * 16 + i;               // wave-uniform
        float af = bf[o], av = bv[o];
        #pragma unroll
        for (int c = 0; c < 64; c++) {
            af = fmaf(Wf[o * 64 + c], xr[c], af);
            av = fmaf(Wv[o * 64 + c], xr[c], av);
        }
        featp[base + i] = af;
        valp[base + i]  = av;
        ss += af * af;
    }
    ssq[q][lane] = ss;
    __syncthreads();
    if (q == 0) {
        float tot = ssq[0][lane] + ssq[1][lane] + ssq[2][lane] + ssq[3][lane];
        invn[r * QPIX + k] = 1.0f / fmaxf(sqrtf(tot), 1e-12f);
    }
}

// ---------------------------------------------------------------------------
// K2 (order-preserving compaction):
//   k2a: per-64-point-chunk quadrant counts (128 chunks)
//   k2c: per-block redundant scan of chunk counts + ranked scatter
// ---------------------------------------------------------------------------
__device__ __forceinline__ int point_quadrant(float px, float py) {
    // rh = 384/2 = 192 exact, rw = 1296/2 = 648 exact
    return ((py > 192.0f) ? 2 : 0) + ((px > 648.0f) ? 1 : 0);
}

__global__ __launch_bounds__(64) void k2a_count(
    const float* __restrict__ points, int* __restrict__ ccnt)
{
    int lane = threadIdx.x;
    int chunk = blockIdx.x;
    float2 p = ((const float2*)points)[chunk * 64 + lane];
    int q = point_quadrant(p.x, p.y);
    #pragma unroll
    for (int r = 0; r < 4; r++) {
        unsigned long long m = __ballot(q == r);
        if (lane == 0) ccnt[chunk * 4 + r] = __popcll(m);
    }
}

__global__ __launch_bounds__(64) void k2c_scatter(
    const float* __restrict__ points, const int* __restrict__ ccnt,
    float* __restrict__ cp, int* __restrict__ slot, int* __restrict__ counts)
{
    int lane = threadIdx.x;
    int chunk = blockIdx.x;

    // redundant per-block scan: prefix over chunks < my chunk, per quadrant
    int c0[4], c1[4], pre[4];
    #pragma unroll
    for (int r = 0; r < 4; r++) {
        c0[r] = ccnt[lane * 4 + r];
        c1[r] = ccnt[(lane + 64) * 4 + r];
        pre[r] = (lane < chunk ? c0[r] : 0) + (lane + 64 < chunk ? c1[r] : 0);
    }
    #pragma unroll
    for (int d = 1; d < 64; d <<= 1) {
        #pragma unroll
        for (int r = 0; r < 4; r++) pre[r] += __shfl_xor(pre[r], d, 64);
    }
    if (chunk == 0) {   // block 0 also publishes the totals
        int full[4];
        #pragma unroll
        for (int r = 0; r < 4; r++) full[r] = c0[r] + c1[r];
        #pragma unroll
        for (int d = 1; d < 64; d <<= 1) {
            #pragma unroll
            for (int r = 0; r < 4; r++) full[r] += __shfl_xor(full[r], d, 64);
        }
        if (lane == 0) {
            #pragma unroll
            for (int r = 0; r < 4; r++) counts[r] = full[r];
        }
    }

    int n = chunk * 64 + lane;
    float2 p = ((const float2*)points)[n];
    int q = point_quadrant(p.x, p.y);
    unsigned long long below = (lane == 0) ? 0ull : (~0ull >> (64 - lane));
    #pragma unroll
    for (int r = 0; r < 4; r++) {
        unsigned long long m = __ballot(q == r);
        if (q == r) {
            int pos = pre[r] + __popcll(m & below);
            ((float2*)cp)[r * MCAP + pos] = p;
            slot[n] = r * MCAP + pos;
        }
    }
}

// ---------------------------------------------------------------------------
// K3: bilinear gather (border clamp) of feat & value at compacted points;
// slot m == K_r is the phantom (0,0) padded row. 4 channel-groups per point
// (256-thread blocks, 16 ch/thread) for 4x the wave count of the old version.
// ---------------------------------------------------------------------------
__global__ __launch_bounds__(256) void k3_gather(
    const float* __restrict__ featp, const float* __restrict__ valp,
    const float* __restrict__ cp, const int* __restrict__ counts,
    float* __restrict__ cn, float* __restrict__ vc)
{
    __shared__ float ssq[64][5];
    int r = blockIdx.y;
    int t = threadIdx.x;
    int g = t & 3, p = t >> 2;          // g: channel group, p: point in tile
    int m = blockIdx.x * 64 + p;
    int K = counts[r];
    int Mr = min(K + 1, MCAP);
    bool active = m < Mr;

    float px = 0.0f, py = 0.0f;
    if (m < K) { float2 pt = ((const float2*)cp)[r * MCAP + m]; px = pt.x; py = pt.y; }

    // mirror reference op order: grid = p/(S-1)*2-1 ; g = (grid+1)*(D/2)-0.5
    float gx = (px / 1295.0f * 2.0f - 1.0f + 1.0f) * 54.0f - 0.5f;
    float gy = (py / 383.0f  * 2.0f - 1.0f + 1.0f) * 16.0f - 0.5f;
    float x0 = floorf(gx), y0 = floorf(gy);
    float wx = gx - x0, wy = gy - y0;
    int x0i = (int)fminf(fmaxf(x0,         0.0f), 107.0f);
    int x1i = (int)fminf(fmaxf(x0 + 1.0f,  0.0f), 107.0f);
    int y0i = (int)fminf(fmaxf(y0,         0.0f), 31.0f);
    int y1i = (int)fminf(fmaxf(y0 + 1.0f,  0.0f), 31.0f);
    float w00 = (1.0f - wx) * (1.0f - wy);
    float w01 = wx * (1.0f - wy);
    float w10 = (1.0f - wx) * wy;
    float w11 = wx * wy;

    int c0 = g * 16;
    size_t b00 = ((size_t)(r * QPIX + y0i * QW + x0i)) * 64 + c0;
    size_t b01 = ((size_t)(r * QPIX + y0i * QW + x1i)) * 64 + c0;
    size_t b10 = ((size_t)(r * QPIX + y1i * QW + x0i)) * 64 + c0;
    size_t b11 = ((size_t)(r * QPIX + y1i * QW + x1i)) * 64 + c0;
    size_t ob  = ((size_t)(r * MCAP + m)) * 64 + c0;

    float fr[16];
    float ss = 0.0f;
    #pragma unroll
    for (int c = 0; c < 16; c += 4) {
        float4 a  = *(const float4*)(featp + b00 + c);
        float4 b_ = *(const float4*)(featp + b01 + c);
        float4 gg = *(const float4*)(featp + b10 + c);
        float4 d  = *(const float4*)(featp + b11 + c);
        float e0 = a.x * w00 + b_.x * w01 + gg.x * w10 + d.x * w11;
        float e1 = a.y * w00 + b_.y * w01 + gg.y * w10 + d.y * w11;
        float e2 = a.z * w00 + b_.z * w01 + gg.z * w10 + d.z * w11;
        float e3 = a.w * w00 + b_.w * w01 + gg.w * w10 + d.w * w11;
        fr[c] = e0; fr[c+1] = e1; fr[c+2] = e2; fr[c+3] = e3;
        ss += e0*e0; ss += e1*e1; ss += e2*e2; ss += e3*e3;
    }
    ssq[p][g] = ss;
    __syncthreads();
    float tot = ssq[p][0] + ssq[p][1] + ssq[p][2] + ssq[p][3];
    float inv = 1.0f / fmaxf(sqrtf(tot), 1e-12f);

    if (active) {
        #pragma unroll
        for (int c = 0; c < 16; c += 4) {
            *(float4*)(cn + ob + c) =
                make_float4(fr[c]*inv, fr[c+1]*inv, fr[c+2]*inv, fr[c+3]*inv);
        }
        #pragma unroll
        for (int c = 0; c < 16; c += 4) {
            float4 a  = *(const float4*)(valp + b00 + c);
            float4 b_ = *(const float4*)(valp + b01 + c);
            float4 gg = *(const float4*)(valp + b10 + c);
            float4 d  = *(const float4*)(valp + b11 + c);
            float4 o;
            o.x = a.x * w00 + b_.x * w01 + gg.x * w10 + d.x * w11;
            o.y = a.y * w00 + b_.y * w01 + gg.y * w10 + d.y * w11;
            o.z = a.z * w00 + b_.z * w01 + gg.z * w10 + d.z * w11;
            o.w = a.w * w00 + b_.w * w01 + gg.w * w10 + d.w * w11;
            *(float4*)(vc + ob + c) = o;
        }
    }
}

// ---------------------------------------------------------------------------
// K4a: cosine-sim running argmax. 128 keys x 64 centers per tile, 2 tiles
// per block. Frag 8 keys x 4 centers. LDS 48 KiB -> 3 blocks/CU.
// All LDS reads <=2-way bank aliased (free). Grid (KT2, CSPL, 4) x 256.
// ---------------------------------------------------------------------------
__global__ __launch_bounds__(256) void k4a_sim(
    const float* __restrict__ featp, const float* __restrict__ invn,
    const float* __restrict__ cn, const int* __restrict__ counts,
    const float* __restrict__ alpha_p, const float* __restrict__ beta_p,
    float* __restrict__ part_s, int* __restrict__ part_m)
{
    __shared__ float Bt[64 * 128];   // [ch][key]     32 KiB
    __shared__ float At[64 * 64];    // [ch][center]  16 KiB

    int r  = blockIdx.z;
    int kt = blockIdx.x;
    int sp = blockIdx.y;
    int k0 = kt * 128;
    int t  = threadIdx.x;
    int tx = t & 15, ty = t >> 4;    // tx -> 8 keys (2 groups of 4), ty -> 4 centers
    int K  = counts[r];
    int Mr = min(K + 1, MCAP);
    int ntiles = (Mr + 63) >> 6;
    int ct0 = sp * 2;
    if (ct0 >= ntiles) return;       // k4b1 only reads partials for s < ceil(ntiles/2)
    int ctEnd = min(ct0 + 2, ntiles);
    float alpha = alpha_p[0], beta = beta_p[0];

    // stage B tile: 128 keys x 64 ch, normalized, channel-major
    {
        int j = t >> 1, hh = (t & 1) * 32;
        float inv = invn[r * QPIX + k0 + j];
        const float* src = featp + ((size_t)(r * QPIX + k0 + j)) * 64 + hh;
        #pragma unroll
        for (int i = 0; i < 32; i += 4) {
            float4 fv = *(const float4*)(src + i);
            Bt[(hh + i + 0) * 128 + j] = fv.x * inv;
            Bt[(hh + i + 1) * 128 + j] = fv.y * inv;
            Bt[(hh + i + 2) * 128 + j] = fv.z * inv;
            Bt[(hh + i + 3) * 128 + j] = fv.w * inv;
        }
    }

    float best_s[8];
    int   best_m[8];
    #pragma unroll
    for (int v = 0; v < 8; v++) { best_s[v] = -INFINITY; best_m[v] = INT_MAX; }

    int aj = t & 63, ack = (t >> 6) * 16;   // A-staging: center row / ch-chunk
    for (int ct = ct0; ct < ctEnd; ct++) {
        // load A sub-tile (64 centers x 16 ch per thread-group) to registers
        float4 pf[4];
        {
            int mg = min(ct * 64 + aj, MCAP - 1);
            const float* src = cn + ((size_t)(r * MCAP + mg)) * 64 + ack;
            #pragma unroll
            for (int i = 0; i < 4; i++) pf[i] = *(const float4*)(src + i * 4);
        }
        if (ct > ct0) __syncthreads();      // prior tile's At reads done
        #pragma unroll
        for (int i = 0; i < 4; i++) {
            At[(ack + i * 4 + 0) * 64 + aj] = pf[i].x;
            At[(ack + i * 4 + 1) * 64 + aj] = pf[i].y;
            At[(ack + i * 4 + 2) * 64 + aj] = pf[i].z;
            At[(ack + i * 4 + 3) * 64 + aj] = pf[i].w;
        }
        __syncthreads();                    // (1st iter: also covers Bt writes)

        float dot[4][8] = {};
        #pragma unroll 4
        for (int cc = 0; cc < 64; cc++) {
            float4 a0 = *(const float4*)(At + cc * 64 + ty * 4);
            float4 b0 = *(const float4*)(Bt + cc * 128 + tx * 4);
            float4 b1 = *(const float4*)(Bt + cc * 128 + 64 + tx * 4);
            float a[4] = {a0.x, a0.y, a0.z, a0.w};
            float b[8] = {b0.x, b0.y, b0.z, b0.w, b1.x, b1.y, b1.z, b1.w};
            #pragma unroll
            for (int u = 0; u < 4; u++) {
                #pragma unroll
                for (int v = 0; v < 8; v++)
                    dot[u][v] = fmaf(a[u], b[v], dot[u][v]);
            }
        }
        // running argmax; m ascending (ct, then u); strict > keeps smallest m
        // on exact fp32 ties (reference first-max rule)
        #pragma unroll
        for (int u = 0; u < 4; u++) {
            int mg = ct * 64 + ty * 4 + u;
            bool valid = mg < Mr;
            #pragma unroll
            for (int v = 0; v < 8; v++) {
                float s = fmaf(alpha, dot[u][v], beta);  // monotone w/ sigmoid
                if (valid && s > best_s[v]) { best_s[v] = s; best_m[v] = mg; }
            }
        }
    }

    // cross-thread (ty) reduce per key; tie -> smaller m; store partials.
    // Reuse Bt as [16][128] scratch after all compute reads are done.
    __syncthreads();
    float* rs = Bt;
    int*   rm = (int*)(Bt + 2048);
    #pragma unroll
    for (int v = 0; v < 8; v++) {
        int col = tx * 4 + (v & 3) + ((v >> 2) << 6);   // key column of this best
        rs[ty * 128 + col] = best_s[v];
        rm[ty * 128 + col] = best_m[v];
    }
    __syncthreads();
    if (t < 128) {
        float bs = rs[t]; int bm = rm[t];
        #pragma unroll
        for (int y = 1; y < 16; y++) {
            float s2 = rs[y * 128 + t]; int m2 = rm[y * 128 + t];
            if (s2 > bs || (s2 == bs && m2 < bm)) { bs = s2; bm = m2; }
        }
        size_t pb = ((size_t)((r * KT2 + kt) * CSPL + sp)) * 128;
        part_s[pb + t] = bs;
        part_m[pb + t] = bm;
    }
}

// ---------------------------------------------------------------------------
// K4b1: reduce split partials per key (tie -> smaller m), sigmoid, and build
// the center histogram (int atomics only). Grid (KT2, 4) x 128.
// ---------------------------------------------------------------------------
__global__ __launch_bounds__(128) void k4b1_argmax(
    const float* __restrict__ part_s, const int* __restrict__ part_m,
    const int* __restrict__ counts,
    int* __restrict__ win_m, float* __restrict__ win_w, int* __restrict__ cnt)
{
    int r  = blockIdx.y;
    int kt = blockIdx.x;
    int t  = threadIdx.x;
    int gk = kt * 128 + t;
    int K  = counts[r];
    int Mr = min(K + 1, MCAP);
    int nS = (((Mr + 63) >> 6) + 1) >> 1;   // active splits

    size_t pb = ((size_t)((r * KT2 + kt) * CSPL)) * 128;
    float bs = -INFINITY; int bm = INT_MAX;
    for (int s = 0; s < nS; s++) {
        float s2 = part_s[pb + (size_t)s * 128 + t];
        int   m2 = part_m[pb + (size_t)s * 128 + t];
        if (s2 > bs || (s2 == bs && m2 < bm)) { bs = s2; bm = m2; }
    }
    if (bm < K) {   // skip phantom / empty winners
        win_m[r * QPIX + gk] = bm;
        win_w[r * QPIX + gk] = 1.0f / (1.0f + expf(-bs));
        atomicAdd(&cnt[r * MCAP + bm], 1);
    } else {
        win_m[r * QPIX + gk] = -1;
    }
}

// ---------------------------------------------------------------------------
// K4b2: per-quadrant exclusive scan of the center histogram (CSR bases).
// Grid (4) x 1024; thread handles 3 consecutive centers (3072 = 1024*3).
// ---------------------------------------------------------------------------
__global__ __launch_bounds__(1024) void k4b2_scan(
    const int* __restrict__ cnt, int* __restrict__ base, int* __restrict__ cursor)
{
    __shared__ int wsum[16];
    int r = blockIdx.x;
    int t = threadIdx.x;
    int i0 = r * MCAP + t * 3;
    int v0 = cnt[i0], v1 = cnt[i0 + 1], v2 = cnt[i0 + 2];
    int s = v0 + v1 + v2;
    int lane = t & 63, w = t >> 6;
    int incl = s;
    #pragma unroll
    for (int d = 1; d < 64; d <<= 1) {
        int n = __shfl_up(incl, d, 64);
        if (lane >= d) incl += n;
    }
    if (lane == 63) wsum[w] = incl;
    __syncthreads();
    int wbase = 0;
    for (int i = 0; i < w; i++) wbase += wsum[i];
    int excl = wbase + incl - s;
    base[i0]     = excl;            cursor[i0]     = excl;
    base[i0 + 1] = excl + v0;       cursor[i0 + 1] = excl + v0;
    base[i0 + 2] = excl + v0 + v1;  cursor[i0 + 2] = excl + v0 + v1;
}

// ---------------------------------------------------------------------------
// K4b3: scatter key ids into per-center CSR lists. Grid (KT2, 4) x 128.
// ---------------------------------------------------------------------------
__global__ __launch_bounds__(128) void k4b3_scatter(
    const int* __restrict__ win_m, int* __restrict__ cursor, int* __restrict__ klist)
{
    int r  = blockIdx.y;
    int gk = blockIdx.x * 128 + threadIdx.x;
    int bm = win_m[r * QPIX + gk];
    if (bm >= 0) {
        int pos = atomicAdd(&cursor[r * MCAP + bm], 1);
        klist[r * QPIX + pos] = gk;
    }
}

// ---------------------------------------------------------------------------
// K4c: per-center gather-sum of winner values; non-atomic agg/denom writes.
// One wave per center. Grid (MCAP/4, 4) x 256.
// ---------------------------------------------------------------------------
__global__ __launch_bounds__(256) void k4c_agg(
    const int* __restrict__ cnt, const int* __restrict__ base,
    const int* __restrict__ klist, const float* __restrict__ win_w,
    const float* __restrict__ valp,
    float* __restrict__ agg, float* __restrict__ denom)
{
    int r = blockIdx.y;
    int m = blockIdx.x * 4 + (threadIdx.x >> 6);
    int lane = threadIdx.x & 63;
    int ci = r * MCAP + m;
    int n = cnt[ci];
    if (n == 0) return;              // agg/denom stay zero (k1 zeroed)
    int b = base[ci];
    float acc = 0.0f, ds = 0.0f;
    for (int i = 0; i < n; i++) {
        int gk = klist[r * QPIX + b + i];
        float w = win_w[r * QPIX + gk];
        acc = fmaf(w, valp[((size_t)(r * QPIX + gk)) * 64 + lane], acc);
        ds += w;
    }
    agg[((size_t)ci) * 64 + lane] = acc;
    if (lane == 0) denom[ci] = ds;
}

// ---------------------------------------------------------------------------
// K5: per-point output + projection + transposed store [1,64,1,8192].
// 32 points per block (8 passes of 4) so Wp is staged once per block.
// ---------------------------------------------------------------------------
__global__ __launch_bounds__(256) void k5_out(
    const float* __restrict__ agg, const float* __restrict__ vc,
    const float* __restrict__ denom, const int* __restrict__ slot,
    const float* __restrict__ Wp, const float* __restrict__ bp,
    float* __restrict__ out)
{
    __shared__ float WT[64 * 65];
    __shared__ float ov[4][68];
    __shared__ float res[4][64];
    int t = threadIdx.x;
    {
        int o = t >> 2, cq = (t & 3) * 16;
        #pragma unroll
        for (int i = 0; i < 16; i += 4) {
            float4 wv = *(const float4*)(Wp + o * 64 + cq + i);
            WT[(cq + i + 0) * 65 + o] = wv.x;
            WT[(cq + i + 1) * 65 + o] = wv.y;
            WT[(cq + i + 2) * 65 + o] = wv.z;
            WT[(cq + i + 3) * 65 + o] = wv.w;
        }
    }
    int p = t >> 6, c = t & 63;
    for (int pp = 0; pp < 8; pp++) {
        int n = blockIdx.x * 32 + pp * 4 + p;
        int sl = slot[n];
        float d = denom[sl] + 1.0f;
        float o_v = (agg[(size_t)sl * 64 + c] + vc[(size_t)sl * 64 + c]) / d;
        ov[p][c] = o_v;
        unsigned long long nz = __ballot(o_v != 0.0f);   // wave == point
        __syncthreads();   // ov ready (1st iter: also covers WT staging)
        float acc = bp[c];
        #pragma unroll
        for (int cc = 0; cc < 64; cc++)
            acc = fmaf(ov[p][cc], WT[cc * 65 + c], acc);
        res[p][c] = (nz != 0ull) ? acc : 0.0f;
        __syncthreads();   // res ready; ov reads done before next-pass writes
        if (t < 64) {
            float4 val = make_float4(res[0][t], res[1][t], res[2][t], res[3][t]);
            *(float4*)(out + (size_t)t * NPTS + blockIdx.x * 32 + pp * 4) = val;
        }
    }
}

// ---------------------------------------------------------------------------
extern "C" void kernel_launch(void* const* d_in, const int* in_sizes, int n_in,
                              void* d_out, int out_size, void* d_ws, size_t ws_size,
                              hipStream_t stream) {
    const float* points = (const float*)d_in[0];
    const float* x      = (const float*)d_in[1];
    const float* Wf     = (const float*)d_in[2];
    const float* bf     = (const float*)d_in[3];
    const float* Wv     = (const float*)d_in[4];
    const float* bv     = (const float*)d_in[5];
    const float* Wp     = (const float*)d_in[6];
    const float* bp     = (const float*)d_in[7];
    const float* alpha  = (const float*)d_in[8];
    const float* beta   = (const float*)d_in[9];
    float* out = (float*)d_out;

    float* ws    = (float*)d_ws;
    float* featp = ws;                        // 884736
    float* valp  = featp + 884736;            // 884736
    float* cn    = valp  + 884736;            // 786432 (4*MCAP*64)
    float* vc    = cn    + 786432;            // 786432
    float* agg   = vc    + 786432;            // 786432  (zeroed by k1)
    float* denom = agg   + 786432;            // 12288   (zeroed by k1)
    int*   cnt   = (int*)(denom + 12288);     // 12288   (zeroed by k1)
    float* invn  = (float*)(cnt + 12288);     // 13824
    float* cp    = invn  + 13824;             // 24576 (2*4*MCAP)
    float* part_s= cp    + 24576;             // 331776 (4*27*24*128)
    int*   part_m= (int*)(part_s + 331776);   // 331776
    int*   ccnt  = part_m + 331776;           // 512
    int*   counts= ccnt   + 512;              // 16
    int*   slot  = counts + 16;               // 8192
    int*   win_m = slot   + 8192;             // 13824
    float* win_w = (float*)(win_m + 13824);   // 13824
    int*   basei = (int*)(win_w + 13824);     // 12288
    int*   cursor= basei  + 12288;            // 12288
    int*   klist = cursor + 12288;            // 13824
    // total ~17 MB of d_ws

    k1_linmaps<<<216, 256, 0, stream>>>(x, Wf, bf, Wv, bv, featp, valp, invn, agg);
    k2a_count  <<<128, 64, 0, stream>>>(points, ccnt);
    k2c_scatter<<<128, 64, 0, stream>>>(points, ccnt, cp, slot, counts);
    k3_gather<<<dim3(MCAP / 64, 4), 256, 0, stream>>>(featp, valp, cp, counts, cn, vc);
    k4a_sim<<<dim3(KT2, CSPL, 4), 256, 0, stream>>>(featp, invn, cn, counts,
                                                    alpha, beta, part_s, part_m);
    k4b1_argmax<<<dim3(KT2, 4), 128, 0, stream>>>(part_s, part_m, counts,
                                                  win_m, win_w, cnt);
    k4b2_scan<<<4, 1024, 0, stream>>>(cnt, basei, cursor);
    k4b3_scatter<<<dim3(KT2, 4), 128, 0, stream>>>(win_m, cursor, klist);
    k4c_agg<<<dim3(MCAP / 4, 4), 256, 0, stream>>>(cnt, basei, klist, win_w,
                                                   valp, agg, denom);
    k5_out<<<NPTS / 32, 256, 0, stream>>>(agg, vc, denom, slot, Wp, bp, out);
}